// Round 2
// baseline (1104.382 us; speedup 1.0000x reference)
//
#include <hip/hip_runtime.h>
#include <hip/hip_bf16.h>
#include <math.h>
#include <cstdint>

// ---------------------------------------------------------------------------
// 3-layer MLP (Linear+GELU ×3), bf16 MFMA compute, fp32 in/out.
//
// R2: port to the 256x256 8-phase counted-vmcnt schedule (catalog T3+T4+T5):
//  - 512 threads = 8 waves (2M x 4N), per-wave output 128x64, BK=64.
//  - LDS 128 KiB: 2 dbuf x (A[256][64] + B[256][64]) bf16, chunk-XOR swizzle
//    (row,k) -> row*64 + ((k>>3 ^ (row&7))<<3) + (k&7)  [0 conflicts, proven].
//  - Per K-tile, 4 phases (q0..q3); each phase: stage ONE 128-row half-tile
//    (2 global_load_lds/thread) + ds_read one register subtile, raw s_barrier,
//    lgkmcnt(0), setprio(1), 16 MFMA, setprio(0), raw s_barrier.
//  - vmcnt(4) ONCE per K-tile (end of q3): 2 half-tiles stay in flight across
//    the tile boundary; never drained to 0 in steady state.
//  - Region schedule (stage target vs last reader, barrier-separated):
//      B0(t) read q0-q1  -> overwritten by B0(t+2) at q2(t)   [2 barriers later]
//      B1(t) read q0-q1  -> overwritten by B1(t+2) at q3(t)
//      A0/A1(t) read q0-q2 -> overwritten by A0/A1(t+1) at q0/q1(t) of NEXT buf
//  - obs pre-converted fp32->bf16 (same RNE rounding => identical numerics);
//    all layers now use the pure global_load_lds path (no VALU cvt in loop).
//  - Keep: XCD-chunked remap, j-inner epilogue stores, exact-erf GELU.
// ---------------------------------------------------------------------------

typedef __bf16 bf16_t;
typedef __attribute__((ext_vector_type(8))) __bf16 bf16x8;
typedef __attribute__((ext_vector_type(4))) float f32x4;
typedef __attribute__((ext_vector_type(4))) unsigned short u16x4;

#define BK 64
#define TILE_ELEMS (256 * 64)   // one A or B tile (256 rows x 64 k) in elements

__device__ inline unsigned short f2bf_rne(float f) {
    unsigned int u = __builtin_bit_cast(unsigned int, f);
    u += 0x7fffu + ((u >> 16) & 1u);   // round-to-nearest-even
    return (unsigned short)(u >> 16);
}

__device__ inline float gelu_erf(float x) {
    return 0.5f * x * (1.0f + erff(x * 0.7071067811865475f));
}

__device__ inline void gload_lds16(const void* g, void* l) {
    auto gp = reinterpret_cast<const __attribute__((address_space(1))) unsigned int*>(
        reinterpret_cast<uintptr_t>(g));
    auto lp = reinterpret_cast<__attribute__((address_space(3))) unsigned int*>(
        reinterpret_cast<uintptr_t>(l));
    __builtin_amdgcn_global_load_lds(gp, lp, 16, 0, 0);
}

// ---- register-subtile loads / MFMA bursts (all indices compile-time) -------
#define LOADA(QM)                                                               \
    _Pragma("unroll") for (int i = 0; i < 4; ++i)                               \
    _Pragma("unroll") for (int s = 0; s < 2; ++s) {                             \
        const int r_ = wm + (QM) * 64 + i * 16 + lrow;                          \
        a_fr[i][s] = *(const bf16x8*)(cA + r_ * BK + (((s * 4 + quad) ^ swz) << 3)); \
    }

#define LOADB(DST, QN)                                                          \
    _Pragma("unroll") for (int j = 0; j < 2; ++j)                               \
    _Pragma("unroll") for (int s = 0; s < 2; ++s) {                             \
        const int r_ = wn + (QN) * 32 + j * 16 + lrow;                          \
        DST[j][s] = *(const bf16x8*)(cB + r_ * BK + (((s * 4 + quad) ^ swz) << 3)); \
    }

#define MMA16(QM, QN, BFR)                                                      \
    _Pragma("unroll") for (int i = 0; i < 4; ++i)                               \
    _Pragma("unroll") for (int j = 0; j < 2; ++j)                               \
    _Pragma("unroll") for (int s = 0; s < 2; ++s)                               \
        acc[(QM) * 4 + i][(QN) * 2 + j] = __builtin_amdgcn_mfma_f32_16x16x32_bf16( \
            a_fr[i][s], BFR[j][s], acc[(QM) * 4 + i][(QN) * 2 + j], 0, 0, 0);

// C = gelu(A[M,K] @ B[N,K]^T + bias), A bf16, C bf16 or fp32.
// Grid: (N/256, M/256), 512 threads.
template <bool OUT_BF16>
__global__ __launch_bounds__(512, 2)
void gemm_bias_gelu(const bf16_t* __restrict__ A,     // [M,K] bf16
                    const bf16_t* __restrict__ B,     // [N,K] bf16
                    const float* __restrict__ bias,   // [N]
                    void* __restrict__ Cv,            // [M,N]
                    int M, int N, int K)
{
    __shared__ __align__(16) bf16_t lA[2 * TILE_ELEMS];   // 64 KiB
    __shared__ __align__(16) bf16_t lB[2 * TILE_ELEMS];   // 64 KiB

    const int tid  = threadIdx.x;
    const int wave = tid >> 6;
    const int lane = tid & 63;
    const int lrow = lane & 15;   // MFMA row/col within 16
    const int quad = lane >> 4;   // k-group of 8
    const int swz  = lrow & 7;    // read swizzle (row&7 == lrow&7)

    // ---- XCD-chunked remap (bijective: nwg % 8 == 0 for all layers)
    const int gx  = gridDim.x;
    const int nwg = gx * gridDim.y;
    int bid = blockIdx.y * gx + blockIdx.x;
    if ((nwg & 7) == 0) {
        const int cpx = nwg >> 3;
        bid = (bid & 7) * cpx + (bid >> 3);
    }
    const int col0 = (bid % gx) * 256;
    const int row0 = (bid / gx) * 256;

    const int wm = (wave >> 2) * 128;   // M-group: 2 waves of 128 rows
    const int wn = (wave & 3) * 64;     // N-group: 4 waves of 64 cols

    // staging: lane l fetches global chunk (l&7)^(l>>3) of row (l>>3)
    const int srow = lane >> 3;
    const int gchk = (lane & 7) ^ srow;

    const int NT = K >> 6;
    const bf16_t* A0p = A + (size_t)row0 * K;
    const bf16_t* B0p = B + (size_t)col0 * K;

    // stage half-tile: half 0=A rows 0-127, 1=A rows 128-255, 2=B0, 3=B1.
    // Each wave stages its own 16 rows (2 x global_load_lds of 8 rows).
    auto stage_half = [&](int tile, int half) {
        if (tile >= NT) return;
        const int k0   = tile << 6;
        const bool isA = half < 2;
        const int rb   = (half & 1) * 128 + wave * 16;
        const bf16_t* g = (isA ? A0p : B0p) + (size_t)(rb + srow) * K + k0 + gchk * 8;
        bf16_t* l = (isA ? lA : lB) + (tile & 1) * TILE_ELEMS + rb * BK;
        #pragma unroll
        for (int c = 0; c < 2; ++c) {
            gload_lds16(g, l);
            g += (size_t)8 * K;
            l += 8 * BK;
        }
    };

    f32x4  acc[8][4] = {};
    bf16x8 a_fr[4][2];
    bf16x8 b_fr0[2][2], b_fr1[2][2];

    // ---- prologue: tile0 (B0,B1,A0,A1) + tile1 (B0,B1); keep 2 halves in flight
    stage_half(0, 2); stage_half(0, 3); stage_half(0, 0); stage_half(0, 1);
    stage_half(1, 2); stage_half(1, 3);
    asm volatile("s_waitcnt vmcnt(4)" ::: "memory");
    __builtin_amdgcn_s_barrier();

    for (int t = 0; t < NT; ++t) {
        const bf16_t* cA = lA + (t & 1) * TILE_ELEMS;
        const bf16_t* cB = lB + (t & 1) * TILE_ELEMS;

        // -- q0: stage A0(t+1) | read A(qm0), B(qn0) | MFMA (0,0)
        stage_half(t + 1, 0);
        LOADA(0)
        LOADB(b_fr0, 0)
        __builtin_amdgcn_s_barrier();
        asm volatile("s_waitcnt lgkmcnt(0)" ::: "memory");
        __builtin_amdgcn_s_setprio(1);
        MMA16(0, 0, b_fr0)
        __builtin_amdgcn_s_setprio(0);
        __builtin_amdgcn_s_barrier();

        // -- q1: stage A1(t+1) | read B(qn1) | MFMA (0,1)
        stage_half(t + 1, 1);
        LOADB(b_fr1, 1)
        __builtin_amdgcn_s_barrier();
        asm volatile("s_waitcnt lgkmcnt(0)" ::: "memory");
        __builtin_amdgcn_s_setprio(1);
        MMA16(0, 1, b_fr1)
        __builtin_amdgcn_s_setprio(0);
        __builtin_amdgcn_s_barrier();

        // -- q2: stage B0(t+2) (B0(t) reads done at q1) | read A(qm1) | MFMA (1,0)
        stage_half(t + 2, 2);
        LOADA(1)
        __builtin_amdgcn_s_barrier();
        asm volatile("s_waitcnt lgkmcnt(0)" ::: "memory");
        __builtin_amdgcn_s_setprio(1);
        MMA16(1, 0, b_fr0)
        __builtin_amdgcn_s_setprio(0);
        __builtin_amdgcn_s_barrier();

        // -- q3: stage B1(t+2) | no reads | MFMA (1,1) | counted vmcnt, publish
        stage_half(t + 2, 3);
        __builtin_amdgcn_s_setprio(1);
        MMA16(1, 1, b_fr1)
        __builtin_amdgcn_s_setprio(0);
        if (t + 2 < NT) {
            asm volatile("s_waitcnt vmcnt(4)" ::: "memory");   // A1(t+1) landed
        } else {
            asm volatile("s_waitcnt vmcnt(0)" ::: "memory");   // tail drain
        }
        __builtin_amdgcn_s_barrier();
    }

    // ---- epilogue: bias + exact-erf GELU + store (j innermost: adjacent
    // 32B segments of one row back-to-back -> L2 write-combining).
    float bv[4];
    #pragma unroll
    for (int nj = 0; nj < 4; ++nj) bv[nj] = bias[col0 + wn + nj * 16 + lrow];

    #pragma unroll
    for (int mi = 0; mi < 8; ++mi) {
        #pragma unroll
        for (int r = 0; r < 4; ++r) {
            const size_t row = (size_t)(row0 + wm + mi * 16 + quad * 4 + r);
            #pragma unroll
            for (int nj = 0; nj < 4; ++nj) {
                const int col = col0 + wn + nj * 16 + lrow;
                float v = acc[mi][nj][r] + bv[nj];
                v = gelu_erf(v);
                if constexpr (OUT_BF16)
                    ((unsigned short*)Cv)[row * N + col] = f2bf_rne(v);
                else
                    ((float*)Cv)[row * N + col] = v;
            }
        }
    }
}

__global__ void cvt_f32_to_bf16(const float* __restrict__ s,
                                unsigned short* __restrict__ d, int n4)
{
    const int i = blockIdx.x * 256 + threadIdx.x;
    if (i < n4) {
        const float4 v = ((const float4*)s)[i];
        u16x4 h;
        h.x = f2bf_rne(v.x); h.y = f2bf_rne(v.y);
        h.z = f2bf_rne(v.z); h.w = f2bf_rne(v.w);
        ((u16x4*)d)[i] = h;
    }
}

extern "C" void kernel_launch(void* const* d_in, const int* in_sizes, int n_in,
                              void* d_out, int out_size, void* d_ws, size_t ws_size,
                              hipStream_t stream)
{
    const int BATCH = 131072, OBS = 1024, H1 = 512, H2 = 512, H3 = 256;

    const float* obs = (const float*)d_in[0];
    const float* W1  = (const float*)d_in[1];
    const float* b1  = (const float*)d_in[2];
    const float* W2  = (const float*)d_in[3];
    const float* b2  = (const float*)d_in[4];
    const float* W3  = (const float*)d_in[5];
    const float* b3  = (const float*)d_in[6];
    float* out = (float*)d_out;

    // workspace (~540 MB): x1 | x2 | obsb | W1b | W2b | W3b
    char* ws = (char*)d_ws;
    bf16_t* x1   = (bf16_t*)ws;                                      // BATCH*H1
    bf16_t* x2   = (bf16_t*)(ws + (size_t)BATCH * H1 * 2);           // BATCH*H2
    bf16_t* obsb = (bf16_t*)(ws + (size_t)BATCH * (H1 + H2) * 2);    // BATCH*OBS
    bf16_t* w1b  = obsb + (size_t)BATCH * OBS;
    bf16_t* w2b  = w1b + (size_t)H1 * OBS;
    bf16_t* w3b  = w2b + (size_t)H2 * H1;

    // weights fp32 -> bf16 (tiny)
    cvt_f32_to_bf16<<<dim3((H1 * OBS / 4 + 255) / 256), 256, 0, stream>>>(W1, (unsigned short*)w1b, H1 * OBS / 4);
    cvt_f32_to_bf16<<<dim3((H2 * H1 / 4 + 255) / 256), 256, 0, stream>>>(W2, (unsigned short*)w2b, H2 * H1 / 4);
    cvt_f32_to_bf16<<<dim3((H3 * H2 / 4 + 255) / 256), 256, 0, stream>>>(W3, (unsigned short*)w3b, H3 * H2 / 4);
    // obs fp32 -> bf16 (BW-bound, removes fp32 staging VALU from L1's loop)
    cvt_f32_to_bf16<<<dim3(BATCH * OBS / 4 / 256), 256, 0, stream>>>(obs, (unsigned short*)obsb, BATCH * OBS / 4);

    // L1: obsb @ W1^T -> x1 (bf16)
    gemm_bias_gelu<true><<<dim3(H1 / 256, BATCH / 256), 512, 0, stream>>>(
        obsb, w1b, b1, x1, BATCH, H1, OBS);
    // L2: x1 @ W2^T -> x2 (bf16)
    gemm_bias_gelu<true><<<dim3(H2 / 256, BATCH / 256), 512, 0, stream>>>(
        x1, w2b, b2, x2, BATCH, H2, H1);
    // L3: x2 @ W3^T -> out (fp32)
    gemm_bias_gelu<false><<<dim3(H3 / 256, BATCH / 256), 512, 0, stream>>>(
        x2, w3b, b3, out, BATCH, H3, H2);
}